// Round 1
// baseline (138.850 us; speedup 1.0000x reference)
//
#include <hip/hip_runtime.h>
#include <hip/hip_bf16.h>
#include <stdint.h>

// Chamfer loss, fused:  dist = ||x||^2 + ||y||^2 - 2 x.y  via bf16 hi/lo-split MFMA
// (K=256 concatenated), per-tile min-reduce, global atomicMin, tiny sum kernel.

typedef __bf16  bf16x8 __attribute__((ext_vector_type(8)));
typedef float   f32x4  __attribute__((ext_vector_type(4)));

#define NPTS 8192
#define DIM  128
#define KC   256   // hi (0..127) | lo (128..255)

__device__ __forceinline__ void gload_lds16(const void* gsrc, void* ldst) {
  __builtin_amdgcn_global_load_lds(
      (const __attribute__((address_space(1))) uint32_t*)(uintptr_t)gsrc,
      (__attribute__((address_space(3))) uint32_t*)(uintptr_t)ldst,
      16, 0, 0);
}

// ---------------------------------------------------------------- prep ----
// One float4 per thread (32 threads/row). Computes row norms (fp32),
// hi/lo bf16 split, inits min arrays to +inf.
__global__ __launch_bounds__(256) void prep_kernel(
    const float* __restrict__ x, const float* __restrict__ y,
    unsigned short* __restrict__ Xc, unsigned short* __restrict__ Yc,
    float* __restrict__ x2, float* __restrict__ y2,
    unsigned int* __restrict__ minx, unsigned int* __restrict__ miny)
{
  const int gt  = blockIdx.x * 256 + threadIdx.x;   // 0 .. 524287
  const int row = gt >> 5;                          // 0 .. 16383
  const int seg = gt & 31;                          // float4 slot in row
  const bool isx = row < NPTS;
  const float* src        = isx ? (x  + (size_t)row * DIM) : (y  + (size_t)(row - NPTS) * DIM);
  unsigned short* dst     = isx ? (Xc + (size_t)row * KC)  : (Yc + (size_t)(row - NPTS) * KC);

  f32x4 v = *reinterpret_cast<const f32x4*>(src + seg * 4);
  float sq = v[0]*v[0] + v[1]*v[1] + v[2]*v[2] + v[3]*v[3];
  #pragma unroll
  for (int m = 1; m <= 16; m <<= 1) sq += __shfl_xor(sq, m);   // 32-lane segmented reduce
  if (seg == 0) { if (isx) x2[row] = sq; else y2[row - NPTS] = sq; }

  unsigned short hb[4], lb[4];
  #pragma unroll
  for (int i = 0; i < 4; ++i) {
    float f = v[i];
    __hip_bfloat16 h = __float2bfloat16(f);
    float hf = __bfloat162float(h);
    __hip_bfloat16 l = __float2bfloat16(f - hf);
    hb[i] = __builtin_bit_cast(unsigned short, h);
    lb[i] = __builtin_bit_cast(unsigned short, l);
  }
  *reinterpret_cast<ushort4*>(dst + seg * 4)       = make_ushort4(hb[0], hb[1], hb[2], hb[3]);
  *reinterpret_cast<ushort4*>(dst + 128 + seg * 4) = make_ushort4(lb[0], lb[1], lb[2], lb[3]);

  if (gt < NPTS)          minx[gt]        = 0x7F800000u;   // +inf
  else if (gt < 2 * NPTS) miny[gt - NPTS] = 0x7F800000u;
}

// ---------------------------------------------------------------- gemm ----
// 128x128 tile, 256 threads = 4 waves (2x2), each wave 64x64 via 4x4 frags
// of mfma_f32_16x16x32_bf16.  K = 256 staged in 4 chunks of 64, double-buffered
// LDS, global_load_lds(16B) with pre-swizzled source; ds_read side applies the
// same XOR swizzle (byte ^= (row&7)<<4) -> even 8-slot bank spread.
__global__ __launch_bounds__(256, 2) void chamfer_gemm(
    const unsigned short* __restrict__ Xc, const unsigned short* __restrict__ Yc,
    const float* __restrict__ x2, const float* __restrict__ y2,
    unsigned int* __restrict__ minx, unsigned int* __restrict__ miny)
{
  __shared__ alignas(16) unsigned short As[2][128 * 64];   // 16 KB each
  __shared__ alignas(16) unsigned short Bs[2][128 * 64];
  __shared__ float x2s[128], y2s[128];
  __shared__ float colminLDS[2][128];   // [wr][col]
  __shared__ float rowminLDS[2][128];   // [wc][row]

  const int tid  = threadIdx.x;
  const int lane = tid & 63;
  const int w    = tid >> 6;
  const int wr   = w >> 1;
  const int wc   = w & 1;
  const int bi   = blockIdx.y;
  const int bj   = blockIdx.x;

  if (tid < 128) x2s[tid]       = x2[bi * 128 + tid];
  else           y2s[tid - 128] = y2[bj * 128 + (tid - 128)];

  // staging geometry: LDS byte L = l*4096 + tid*16  ->  row = l*32 + tid/8,
  // slot = tid&7.  Slot s of row r holds logical kgroup s ^ (r&7)  (source
  // pre-swizzle so the LDS dest stays linear, rule 21).
  const int r32  = tid >> 3;                       // 0..31
  const int kgrp = (tid & 7) ^ (r32 & 7);
  const unsigned short* Abase = Xc + (size_t)(bi * 128 + r32) * KC + kgrp * 8;
  const unsigned short* Bbase = Yc + (size_t)(bj * 128 + r32) * KC + kgrp * 8;

  auto STAGE = [&](int buf, int kt) {
    const unsigned short* Asrc = Abase + kt * 64;
    const unsigned short* Bsrc = Bbase + kt * 64;
    char* Ad = (char*)&As[buf][0] + w * 1024;      // wave-uniform LDS base
    char* Bd = (char*)&Bs[buf][0] + w * 1024;
    #pragma unroll
    for (int l = 0; l < 4; ++l) {
      gload_lds16(Asrc + (size_t)l * 32 * KC, Ad + l * 4096);
      gload_lds16(Bsrc + (size_t)l * 32 * KC, Bd + l * 4096);
    }
  };

  f32x4 acc[4][4] = {};

  STAGE(0, 0);
  __syncthreads();   // drains vmcnt -> buf0 ready

  #pragma unroll
  for (int kt = 0; kt < 4; ++kt) {
    if (kt < 3) STAGE((kt + 1) & 1, kt + 1);       // prefetch next chunk
    const char* Ab = (const char*)&As[kt & 1][0];
    const char* Bb = (const char*)&Bs[kt & 1][0];

    bf16x8 b[4][2];
    #pragma unroll
    for (int ni = 0; ni < 4; ++ni) {
      const int col = wc * 64 + ni * 16 + (lane & 15);
      const int swz = (col & 7) << 4;
      #pragma unroll
      for (int ks = 0; ks < 2; ++ks) {
        const int ofs = (ks * 64 + ((lane >> 4) << 4)) ^ swz;
        b[ni][ks] = *reinterpret_cast<const bf16x8*>(Bb + col * 128 + ofs);
      }
    }
    #pragma unroll
    for (int mi = 0; mi < 4; ++mi) {
      const int rowl = wr * 64 + mi * 16 + (lane & 15);
      const int swz  = (rowl & 7) << 4;
      const bf16x8 a0 = *reinterpret_cast<const bf16x8*>(Ab + rowl * 128 + ((  0 + ((lane >> 4) << 4)) ^ swz));
      const bf16x8 a1 = *reinterpret_cast<const bf16x8*>(Ab + rowl * 128 + (( 64 + ((lane >> 4) << 4)) ^ swz));
      #pragma unroll
      for (int ni = 0; ni < 4; ++ni) {
        acc[mi][ni] = __builtin_amdgcn_mfma_f32_16x16x32_bf16(a0, b[ni][0], acc[mi][ni], 0, 0, 0);
        acc[mi][ni] = __builtin_amdgcn_mfma_f32_16x16x32_bf16(a1, b[ni][1], acc[mi][ni], 0, 0, 0);
      }
    }
    __syncthreads();   // staged loads landed; compute done before buffer reuse
  }

  // ---- epilogue: dist = max(0, x2 + y2 - 2*acc), fused min reductions ----
  f32x4 xv[4]; float yv[4];
  #pragma unroll
  for (int mi = 0; mi < 4; ++mi)
    xv[mi] = *reinterpret_cast<const f32x4*>(&x2s[wr * 64 + mi * 16 + ((lane >> 4) << 2)]);
  #pragma unroll
  for (int ni = 0; ni < 4; ++ni)
    yv[ni] = y2s[wc * 64 + ni * 16 + (lane & 15)];

  #pragma unroll
  for (int mi = 0; mi < 4; ++mi)
    #pragma unroll
    for (int ni = 0; ni < 4; ++ni)
      #pragma unroll
      for (int r = 0; r < 4; ++r)
        acc[mi][ni][r] = fmaxf(0.f, fmaf(-2.f, acc[mi][ni][r], xv[mi][r] + yv[ni]));

  // column mins over this wave's 64 rows (per ni, then fold over lane>>4)
  float cm[4];
  #pragma unroll
  for (int ni = 0; ni < 4; ++ni) {
    float m = 3.0e38f;
    #pragma unroll
    for (int mi = 0; mi < 4; ++mi)
      #pragma unroll
      for (int r = 0; r < 4; ++r)
        m = fminf(m, acc[mi][ni][r]);
    cm[ni] = m;
  }
  {
    const bool hb0 = (lane & 16) != 0;
    float s0 = hb0 ? cm[0] : cm[2];
    float s1 = hb0 ? cm[1] : cm[3];
    float r0 = __shfl_xor(s0, 16);
    float r1 = __shfl_xor(s1, 16);
    float t0 = fminf(hb0 ? cm[2] : cm[0], r0);
    float t1 = fminf(hb0 ? cm[3] : cm[1], r1);
    const bool hb1 = (lane & 32) != 0;
    float s  = hb1 ? t0 : t1;
    float rr = __shfl_xor(s, 32);
    float cfin = fminf(hb1 ? t1 : t0, rr);
    const int ni = (hb0 ? 2 : 0) + (hb1 ? 1 : 0);    // bitrev2(lane>>4)
    colminLDS[wr][wc * 64 + ni * 16 + (lane & 15)] = cfin;
  }

  // row mins: reduce over ni in regs, then log-fold over the 16-lane group
  float rm[16];
  #pragma unroll
  for (int mi = 0; mi < 4; ++mi)
    #pragma unroll
    for (int r = 0; r < 4; ++r)
      rm[mi * 4 + r] = fminf(fminf(acc[mi][0][r], acc[mi][1][r]),
                             fminf(acc[mi][2][r], acc[mi][3][r]));
  #pragma unroll
  for (int b2 = 0; b2 < 4; ++b2) {
    const int  half = 8 >> b2;
    const bool up   = (lane >> b2) & 1;
    #pragma unroll
    for (int i = 0; i < half; ++i) {
      float snd = up ? rm[i] : rm[i + half];
      float rcv = __shfl_xor(snd, 1 << b2);
      rm[i] = fminf(up ? rm[i + half] : rm[i], rcv);
    }
  }
  {
    const int v = ((lane & 1) << 3) | ((lane & 2) << 1) | ((lane & 4) >> 1) | ((lane & 8) >> 3);
    const int row_local = wr * 64 + (v >> 2) * 16 + ((lane >> 4) << 2) + (v & 3);
    rowminLDS[wc][row_local] = rm[0];
  }
  __syncthreads();

  // combine the 2 waves per axis, one atomic per row/col (floats >= 0:
  // uint bit-pattern ordering == float ordering)
  if (tid < 128) {
    float c = fminf(colminLDS[0][tid], colminLDS[1][tid]);
    atomicMin(&miny[bj * 128 + tid], __float_as_uint(c));
  } else {
    const int r = tid - 128;
    float vmin = fminf(rowminLDS[0][r], rowminLDS[1][r]);
    atomicMin(&minx[bi * 128 + r], __float_as_uint(vmin));
  }
}

// ------------------------------------------------------------- finalize ----
__global__ __launch_bounds__(256) void finalize_kernel(
    const unsigned int* __restrict__ minx, const unsigned int* __restrict__ miny,
    float* __restrict__ out)
{
  float s = 0.f;
  for (int i = threadIdx.x; i < NPTS; i += 256)
    s += __uint_as_float(minx[i]) + __uint_as_float(miny[i]);
  #pragma unroll
  for (int m = 32; m >= 1; m >>= 1) s += __shfl_xor(s, m);
  __shared__ float partial[4];
  if ((threadIdx.x & 63) == 0) partial[threadIdx.x >> 6] = s;
  __syncthreads();
  if (threadIdx.x == 0)
    out[0] = (partial[0] + partial[1] + partial[2] + partial[3]) * (1.0f / (float)NPTS);
}

// ---------------------------------------------------------------- launch ----
extern "C" void kernel_launch(void* const* d_in, const int* in_sizes, int n_in,
                              void* d_out, int out_size, void* d_ws, size_t ws_size,
                              hipStream_t stream) {
  (void)in_sizes; (void)n_in; (void)out_size; (void)ws_size;
  const float* x = (const float*)d_in[0];
  const float* y = (const float*)d_in[1];
  char* ws = (char*)d_ws;

  // workspace layout (16B-aligned): Xc 4MB | Yc 4MB | x2 32KB | y2 32KB | minx 32KB | miny 32KB
  unsigned short* Xc  = (unsigned short*)(ws);
  unsigned short* Yc  = (unsigned short*)(ws + 4194304);
  float*          x2  = (float*)(ws + 8388608);
  float*          y2  = (float*)(ws + 8421376);
  unsigned int*   mnx = (unsigned int*)(ws + 8454144);
  unsigned int*   mny = (unsigned int*)(ws + 8486912);
  float*          out = (float*)d_out;

  prep_kernel<<<2048, 256, 0, stream>>>(x, y, Xc, Yc, x2, y2, mnx, mny);
  dim3 grid(64, 64);
  chamfer_gemm<<<grid, 256, 0, stream>>>(Xc, Yc, x2, y2, mnx, mny);
  finalize_kernel<<<1, 256, 0, stream>>>(mnx, mny, out);
}

// Round 2
// 99.770 us; speedup vs baseline: 1.3917x; 1.3917x over previous
//
#include <hip/hip_runtime.h>
#include <hip/hip_bf16.h>
#include <stdint.h>

// Chamfer loss: dist = ||x||^2 + ||y||^2 - 2 x.y via bf16 hi/lo-split MFMA.
// X is pre-scaled by -2 (exact), acc is initialized with x^2+y^2 so the MFMA
// accumulator directly holds the distance; epilogue is pure min-reductions.
// 256x256 tile, 512 threads / 8 waves (2x4), BK=64 double-buffered LDS,
// global_load_lds(16B) with pre-swizzled source + XOR-swizzled ds_read_b128.

typedef __bf16  bf16x8 __attribute__((ext_vector_type(8)));
typedef float   f32x4  __attribute__((ext_vector_type(4)));

#define NPTS 8192
#define DIM  128
#define KC   256   // hi (0..127) | lo (128..255)

__device__ __forceinline__ void gload_lds16(const void* gsrc, void* ldst) {
  __builtin_amdgcn_global_load_lds(
      (const __attribute__((address_space(1))) uint32_t*)(uintptr_t)gsrc,
      (__attribute__((address_space(3))) uint32_t*)(uintptr_t)ldst,
      16, 0, 0);
}

// ---------------------------------------------------------------- prep ----
// One float4 per thread (32 threads/row). Row norms (fp32, of ORIGINAL x),
// hi/lo bf16 split of (-2x) for X / (y) for Y, min arrays -> +inf.
__global__ __launch_bounds__(256) void prep_kernel(
    const float* __restrict__ x, const float* __restrict__ y,
    unsigned short* __restrict__ Xc, unsigned short* __restrict__ Yc,
    float* __restrict__ x2, float* __restrict__ y2,
    unsigned int* __restrict__ minx, unsigned int* __restrict__ miny)
{
  const int gt  = blockIdx.x * 256 + threadIdx.x;   // 0 .. 524287
  const int row = gt >> 5;                          // 0 .. 16383
  const int seg = gt & 31;                          // float4 slot in row
  const bool isx = row < NPTS;
  const float* src        = isx ? (x  + (size_t)row * DIM) : (y  + (size_t)(row - NPTS) * DIM);
  unsigned short* dst     = isx ? (Xc + (size_t)row * KC)  : (Yc + (size_t)(row - NPTS) * KC);

  f32x4 v = *reinterpret_cast<const f32x4*>(src + seg * 4);
  float sq = v[0]*v[0] + v[1]*v[1] + v[2]*v[2] + v[3]*v[3];
  #pragma unroll
  for (int m = 1; m <= 16; m <<= 1) sq += __shfl_xor(sq, m);   // 32-lane segmented reduce
  if (seg == 0) { if (isx) x2[row] = sq; else y2[row - NPTS] = sq; }

  const float scale = isx ? -2.0f : 1.0f;           // fold the -2 into X (exact)
  unsigned short hb[4], lb[4];
  #pragma unroll
  for (int i = 0; i < 4; ++i) {
    float f = scale * v[i];
    __hip_bfloat16 h = __float2bfloat16(f);
    float hf = __bfloat162float(h);
    __hip_bfloat16 l = __float2bfloat16(f - hf);
    hb[i] = __builtin_bit_cast(unsigned short, h);
    lb[i] = __builtin_bit_cast(unsigned short, l);
  }
  *reinterpret_cast<ushort4*>(dst + seg * 4)       = make_ushort4(hb[0], hb[1], hb[2], hb[3]);
  *reinterpret_cast<ushort4*>(dst + 128 + seg * 4) = make_ushort4(lb[0], lb[1], lb[2], lb[3]);

  if (gt < NPTS)          minx[gt]        = 0x7F800000u;   // +inf
  else if (gt < 2 * NPTS) miny[gt - NPTS] = 0x7F800000u;
}

// ---------------------------------------------------------------- gemm ----
__global__ __launch_bounds__(512, 2) void chamfer_gemm(
    const unsigned short* __restrict__ Xc, const unsigned short* __restrict__ Yc,
    const float* __restrict__ x2, const float* __restrict__ y2,
    unsigned int* __restrict__ minx, unsigned int* __restrict__ miny)
{
  __shared__ alignas(16) unsigned short As[2][256 * 64];   // 32 KB each
  __shared__ alignas(16) unsigned short Bs[2][256 * 64];
  // reduce scratch overlaid on As[0] (only touched after its last compute use)
  float* colminLDS = (float*)&As[0][0];          // [2][256]
  float* rowminLDS = (float*)&As[0][0] + 512;    // [4][256]

  const int tid  = threadIdx.x;
  const int lane = tid & 63;
  const int w    = tid >> 6;        // 0..7
  const int wr   = w >> 2;          // 0..1  (rows: wr*128)
  const int wc   = w & 3;           // 0..3  (cols: wc*64)

  // XCD-chunked bijective swizzle: XCD k owns bi in [4k,4k+4), bj sub-grouped by 8
  const int bid   = blockIdx.x;
  const int xcd   = bid & 7;
  const int local = bid >> 3;              // 0..127
  const int bi    = xcd * 4 + ((local >> 3) & 3);
  const int bj    = ((local >> 5) << 3) + (local & 7);

  // staging geometry: LDS byte = row*128 + slot*16 (linear), slot = tid&7,
  // row = l*64 + (tid>>3); source pre-swizzled: kgroup = slot ^ (row&7).
  const int r64  = tid >> 3;               // 0..63
  const int kgrp = (tid & 7) ^ (r64 & 7);
  const unsigned short* Abase = Xc + (size_t)(bi * 256 + r64) * KC + kgrp * 8;
  const unsigned short* Bbase = Yc + (size_t)(bj * 256 + r64) * KC + kgrp * 8;

  auto STAGE = [&](int buf, int kt) {
    const unsigned short* Asrc = Abase + kt * 64;
    const unsigned short* Bsrc = Bbase + kt * 64;
    char* Ad = (char*)&As[buf][0] + w * 1024;      // wave-uniform LDS base
    char* Bd = (char*)&Bs[buf][0] + w * 1024;
    #pragma unroll
    for (int l = 0; l < 4; ++l) {                  // 64 rows per round
      gload_lds16(Asrc + (size_t)l * 64 * KC, Ad + l * 8192);
      gload_lds16(Bsrc + (size_t)l * 64 * KC, Bd + l * 8192);
    }
  };

  // acc init = x2[row] + y2[col]  ->  accumulator IS the distance
  f32x4 acc[8][4];
  {
    f32x4 xv[8]; float yv[4];
    #pragma unroll
    for (int mi = 0; mi < 8; ++mi)
      xv[mi] = *reinterpret_cast<const f32x4*>(x2 + bi * 256 + wr * 128 + mi * 16 + ((lane >> 4) << 2));
    #pragma unroll
    for (int ni = 0; ni < 4; ++ni)
      yv[ni] = y2[bj * 256 + wc * 64 + ni * 16 + (lane & 15)];
    #pragma unroll
    for (int mi = 0; mi < 8; ++mi)
      #pragma unroll
      for (int ni = 0; ni < 4; ++ni)
        #pragma unroll
        for (int r = 0; r < 4; ++r)
          acc[mi][ni][r] = xv[mi][r] + yv[ni];
  }

  STAGE(0, 0);
  __syncthreads();   // drains vmcnt -> buf0 ready

  #pragma unroll
  for (int kt = 0; kt < 4; ++kt) {
    if (kt < 3) STAGE((kt + 1) & 1, kt + 1);       // prefetch next chunk
    const char* Ab = (const char*)&As[kt & 1][0];
    const char* Bb = (const char*)&Bs[kt & 1][0];

    bf16x8 b[4][2];
    #pragma unroll
    for (int ni = 0; ni < 4; ++ni) {
      const int col = wc * 64 + ni * 16 + (lane & 15);
      const int swz = (col & 7) << 4;
      #pragma unroll
      for (int ks = 0; ks < 2; ++ks) {
        const int ofs = (ks * 64 + ((lane >> 4) << 4)) ^ swz;
        b[ni][ks] = *reinterpret_cast<const bf16x8*>(Bb + col * 128 + ofs);
      }
    }
    #pragma unroll
    for (int mi = 0; mi < 8; ++mi) {
      const int rowl = wr * 128 + mi * 16 + (lane & 15);
      const int swz  = (rowl & 7) << 4;
      const bf16x8 a0 = *reinterpret_cast<const bf16x8*>(Ab + rowl * 128 + ((  0 + ((lane >> 4) << 4)) ^ swz));
      const bf16x8 a1 = *reinterpret_cast<const bf16x8*>(Ab + rowl * 128 + (( 64 + ((lane >> 4) << 4)) ^ swz));
      #pragma unroll
      for (int ni = 0; ni < 4; ++ni) {
        acc[mi][ni] = __builtin_amdgcn_mfma_f32_16x16x32_bf16(a0, b[ni][0], acc[mi][ni], 0, 0, 0);
        acc[mi][ni] = __builtin_amdgcn_mfma_f32_16x16x32_bf16(a1, b[ni][1], acc[mi][ni], 0, 0, 0);
      }
    }
    __syncthreads();   // staged loads landed; compute done before buffer reuse
  }

  // ---- epilogue: acc already holds dist (pre-clamp); pure min reductions ----
  // column mins over this wave's 128 rows (per ni, then fold over lane>>4)
  float cm[4];
  #pragma unroll
  for (int ni = 0; ni < 4; ++ni) {
    float m = 3.0e38f;
    #pragma unroll
    for (int mi = 0; mi < 8; ++mi)
      #pragma unroll
      for (int r = 0; r < 4; ++r)
        m = fminf(m, acc[mi][ni][r]);
    cm[ni] = m;
  }
  {
    const bool hb0 = (lane & 16) != 0;
    float s0 = hb0 ? cm[0] : cm[2];
    float s1 = hb0 ? cm[1] : cm[3];
    float r0 = __shfl_xor(s0, 16);
    float r1 = __shfl_xor(s1, 16);
    float t0 = fminf(hb0 ? cm[2] : cm[0], r0);
    float t1 = fminf(hb0 ? cm[3] : cm[1], r1);
    const bool hb1 = (lane & 32) != 0;
    float s  = hb1 ? t0 : t1;
    float rr = __shfl_xor(s, 32);
    float cfin = fminf(hb1 ? t1 : t0, rr);
    const int ni = (hb0 ? 2 : 0) + (hb1 ? 1 : 0);    // bitrev2(lane>>4)
    colminLDS[wr * 256 + wc * 64 + ni * 16 + (lane & 15)] = cfin;
  }

  // row mins: reduce over ni in regs (32 values), 4-step fold over lane&15
  float rm[32];
  #pragma unroll
  for (int mi = 0; mi < 8; ++mi)
    #pragma unroll
    for (int r = 0; r < 4; ++r)
      rm[mi * 4 + r] = fminf(fminf(acc[mi][0][r], acc[mi][1][r]),
                             fminf(acc[mi][2][r], acc[mi][3][r]));
  #pragma unroll
  for (int b2 = 0; b2 < 4; ++b2) {
    const int  half = 16 >> b2;
    const bool up   = (lane >> b2) & 1;
    #pragma unroll
    for (int i = 0; i < half; ++i) {
      float snd = up ? rm[i] : rm[i + half];
      float rcv = __shfl_xor(snd, 1 << b2);
      rm[i] = fminf(up ? rm[i + half] : rm[i], rcv);
    }
  }
  {
    // surviving rm[e], e in {0,1}: idx = l0<<4 | l1<<3 | l2<<2 | l3<<1 | e
    const int base = ((lane & 1) << 4) | ((lane & 2) << 2) | (lane & 4) | ((lane & 8) >> 2);
    #pragma unroll
    for (int e = 0; e < 2; ++e) {
      const int idx = base | e;
      const int row_local = wr * 128 + (idx >> 2) * 16 + ((lane >> 4) << 2) + (idx & 3);
      rowminLDS[wc * 256 + row_local] = rm[e];
    }
  }
  __syncthreads();

  // combine waves, clamp at 0 (commutes with min), one atomic per row/col
  if (tid < 256) {
    float c = fminf(colminLDS[tid], colminLDS[256 + tid]);
    atomicMin(&miny[bj * 256 + tid], __float_as_uint(fmaxf(c, 0.f)));
  } else {
    const int r = tid - 256;
    float v = fminf(fminf(rowminLDS[r], rowminLDS[256 + r]),
                    fminf(rowminLDS[512 + r], rowminLDS[768 + r]));
    atomicMin(&minx[bi * 256 + r], __float_as_uint(fmaxf(v, 0.f)));
  }
}

// ------------------------------------------------------------- finalize ----
__global__ __launch_bounds__(256) void finalize_kernel(
    const unsigned int* __restrict__ minx, const unsigned int* __restrict__ miny,
    float* __restrict__ out)
{
  // all stored patterns are non-negative floats; reinterpret directly
  const f32x4* mx = (const f32x4*)minx;
  const f32x4* my = (const f32x4*)miny;
  float s = 0.f;
  for (int i = threadIdx.x; i < NPTS / 4; i += 256) {
    f32x4 a = mx[i], b = my[i];
    s += (a[0] + a[1] + a[2] + a[3]) + (b[0] + b[1] + b[2] + b[3]);
  }
  #pragma unroll
  for (int m = 32; m >= 1; m >>= 1) s += __shfl_xor(s, m);
  __shared__ float partial[4];
  if ((threadIdx.x & 63) == 0) partial[threadIdx.x >> 6] = s;
  __syncthreads();
  if (threadIdx.x == 0)
    out[0] = (partial[0] + partial[1] + partial[2] + partial[3]) * (1.0f / (float)NPTS);
}

// ---------------------------------------------------------------- launch ----
extern "C" void kernel_launch(void* const* d_in, const int* in_sizes, int n_in,
                              void* d_out, int out_size, void* d_ws, size_t ws_size,
                              hipStream_t stream) {
  (void)in_sizes; (void)n_in; (void)out_size; (void)ws_size;
  const float* x = (const float*)d_in[0];
  const float* y = (const float*)d_in[1];
  char* ws = (char*)d_ws;

  // workspace layout (16B-aligned): Xc 4MB | Yc 4MB | x2 32KB | y2 32KB | minx 32KB | miny 32KB
  unsigned short* Xc  = (unsigned short*)(ws);
  unsigned short* Yc  = (unsigned short*)(ws + 4194304);
  float*          x2  = (float*)(ws + 8388608);
  float*          y2  = (float*)(ws + 8421376);
  unsigned int*   mnx = (unsigned int*)(ws + 8454144);
  unsigned int*   mny = (unsigned int*)(ws + 8486912);
  float*          out = (float*)d_out;

  prep_kernel<<<2048, 256, 0, stream>>>(x, y, Xc, Yc, x2, y2, mnx, mny);
  chamfer_gemm<<<1024, 512, 0, stream>>>(Xc, Yc, x2, y2, mnx, mny);
  finalize_kernel<<<1, 256, 0, stream>>>(mnx, mny, out);
}